// Round 1
// baseline (197.644 us; speedup 1.0000x reference)
//
#include <hip/hip_runtime.h>
#include <hip/hip_bf16.h>
#include <math.h>

#define B_ 8
#define T_ 2048
#define C_ 1024
#define H_ 64

typedef __attribute__((ext_vector_type(8))) __bf16 bf16x8;
typedef __attribute__((ext_vector_type(4))) float f32x4;

static __device__ inline unsigned short f2bf_u(float f) {
    __bf16 b = (__bf16)f;
    return __builtin_bit_cast(unsigned short, b);
}

// ---- pack Wq|Wk|Wv fp32 [1024][64] -> Wp bf16 [kt][n][32], n in [0,192) ----
__global__ void prep_w_kernel(const float* __restrict__ Wq,
                              const float* __restrict__ Wk,
                              const float* __restrict__ Wv,
                              unsigned short* __restrict__ Wp) {
    int idx = blockIdx.x * 256 + threadIdx.x;
    if (idx >= C_ * 192) return;
    int k = idx / 192;
    int n = idx % 192;
    const float* W = (n < 64) ? Wq : (n < 128) ? Wk : Wv;
    float val = W[k * 64 + (n & 63)];
    Wp[((size_t)(k >> 5) * 192 + n) * 32 + (k & 31)] = f2bf_u(val);
}

// ---- qkv projection: block = 64 rows x 192 cols, 4 waves x (16 rows x 192) ----
__global__ __launch_bounds__(256) void proj_kernel(
        const float* __restrict__ x, const unsigned short* __restrict__ Wp,
        unsigned short* __restrict__ q, unsigned short* __restrict__ k,
        unsigned short* __restrict__ vT) {
    const int wave = threadIdx.x >> 6;
    const int lane = threadIdx.x & 63;
    const int col  = lane & 15;
    const int quad = lane >> 4;
    const int row0 = blockIdx.x * 64 + wave * 16;
    const float* xrow = x + (size_t)(row0 + col) * C_ + quad * 8;

    f32x4 acc[12];
    #pragma unroll
    for (int i = 0; i < 12; i++) acc[i] = (f32x4){0.f, 0.f, 0.f, 0.f};

    for (int kt = 0; kt < 32; kt++) {
        const float4* xp = (const float4*)(xrow + kt * 32);
        float4 x0 = xp[0];
        float4 x1 = xp[1];
        bf16x8 a;
        a[0] = (__bf16)x0.x; a[1] = (__bf16)x0.y; a[2] = (__bf16)x0.z; a[3] = (__bf16)x0.w;
        a[4] = (__bf16)x1.x; a[5] = (__bf16)x1.y; a[6] = (__bf16)x1.z; a[7] = (__bf16)x1.w;
        const unsigned short* wb = Wp + ((size_t)kt * 192 + col) * 32 + quad * 8;
        #pragma unroll
        for (int n = 0; n < 12; n++) {
            bf16x8 bfrag = *(const bf16x8*)(wb + n * (16 * 32));
            acc[n] = __builtin_amdgcn_mfma_f32_16x16x32_bf16(a, bfrag, acc[n], 0, 0, 0);
        }
    }
    // epilogue: C/D layout col=lane&15, row=quad*4+reg  [verified m89/m91]
    const int bi   = row0 >> 11;
    const int trow = row0 & 2047;
    #pragma unroll
    for (int n = 0; n < 8; n++) {
        unsigned short* dst = (n < 4) ? q : k;
        int cc = (n & 3) * 16 + col;
        #pragma unroll
        for (int r = 0; r < 4; r++) {
            int grow = row0 + quad * 4 + r;
            dst[(size_t)grow * 64 + cc] = f2bf_u(acc[n][r]);
        }
    }
    #pragma unroll
    for (int n = 8; n < 12; n++) {
        int hh = (n - 8) * 16 + col;
        #pragma unroll
        for (int r = 0; r < 4; r++) {
            int t = trow + quad * 4 + r;
            vT[((size_t)bi * 64 + hh) * T_ + t] = f2bf_u(acc[n][r]);
        }
    }
}

// ---- flash attention, causal; 16 queries/wave, 32 keys/iter ----
__global__ __launch_bounds__(256) void attn_kernel(
        const unsigned short* __restrict__ q, const unsigned short* __restrict__ k,
        const unsigned short* __restrict__ vT, float* __restrict__ out) {
    __shared__ unsigned short plds[4][16][32];   // per-wave P tile (C->A transpose)
    const int wave = threadIdx.x >> 6;
    const int lane = threadIdx.x & 63;
    const int col  = lane & 15;
    const int quad = lane >> 4;
    const int bi = blockIdx.x >> 5;              // 32 blocks per batch
    const int t0 = (blockIdx.x & 31) * 64 + wave * 16;
    const unsigned short* qb = q  + (size_t)bi * T_ * 64;
    const unsigned short* kb = k  + (size_t)bi * T_ * 64;
    const unsigned short* vb = vT + (size_t)bi * 64 * T_;

    // Q fragments (A layout: m=lane&15, k=quad*8+j), kept in regs for all key tiles
    bf16x8 qf0 = *(const bf16x8*)(qb + (size_t)(t0 + col) * 64 + quad * 8);
    bf16x8 qf1 = *(const bf16x8*)(qb + (size_t)(t0 + col) * 64 + 32 + quad * 8);

    f32x4 o[4];
    #pragma unroll
    for (int i = 0; i < 4; i++) o[i] = (f32x4){0.f, 0.f, 0.f, 0.f};
    float mr[4] = {-1e30f, -1e30f, -1e30f, -1e30f};
    float lr[4] = {0.f, 0.f, 0.f, 0.f};
    const float cs = 0.03125f * 1.44269504088896f;   // C^-0.5 * log2(e), logits in base 2

    const int kend = t0 + 16;
    for (int s0 = 0; s0 < kend; s0 += 32) {
        // K fragments (B layout from row-major K[t][h]: B^T pattern, contiguous 16B)
        bf16x8 kf00 = *(const bf16x8*)(kb + (size_t)(s0 + col) * 64 + quad * 8);
        bf16x8 kf01 = *(const bf16x8*)(kb + (size_t)(s0 + col) * 64 + 32 + quad * 8);
        bf16x8 kf10 = *(const bf16x8*)(kb + (size_t)(s0 + 16 + col) * 64 + quad * 8);
        bf16x8 kf11 = *(const bf16x8*)(kb + (size_t)(s0 + 16 + col) * 64 + 32 + quad * 8);
        f32x4 sa = (f32x4){0.f, 0.f, 0.f, 0.f};
        f32x4 sb = (f32x4){0.f, 0.f, 0.f, 0.f};
        sa = __builtin_amdgcn_mfma_f32_16x16x32_bf16(qf0, kf00, sa, 0, 0, 0);
        sa = __builtin_amdgcn_mfma_f32_16x16x32_bf16(qf1, kf01, sa, 0, 0, 0);
        sb = __builtin_amdgcn_mfma_f32_16x16x32_bf16(qf0, kf10, sb, 0, 0, 0);
        sb = __builtin_amdgcn_mfma_f32_16x16x32_bf16(qf1, kf11, sb, 0, 0, 0);

        float alpha[4];
        #pragma unroll
        for (int r = 0; r < 4; r++) {
            int qrow = t0 + quad * 4 + r;
            float v0 = (s0 + col      <= qrow) ? sa[r] * cs : -1e30f;
            float v1 = (s0 + 16 + col <= qrow) ? sb[r] * cs : -1e30f;
            float mx = fmaxf(v0, v1);
            mx = fmaxf(mx, __shfl_xor(mx, 1));
            mx = fmaxf(mx, __shfl_xor(mx, 2));
            mx = fmaxf(mx, __shfl_xor(mx, 4));
            mx = fmaxf(mx, __shfl_xor(mx, 8));
            float mnew = fmaxf(mr[r], mx);
            alpha[r] = exp2f(mr[r] - mnew);
            mr[r] = mnew;
            float p0 = exp2f(v0 - mnew);
            float p1 = exp2f(v1 - mnew);
            float ps = p0 + p1;
            ps += __shfl_xor(ps, 1);
            ps += __shfl_xor(ps, 2);
            ps += __shfl_xor(ps, 4);
            ps += __shfl_xor(ps, 8);
            lr[r] = lr[r] * alpha[r] + ps;
            plds[wave][quad * 4 + r][col]      = f2bf_u(p0);
            plds[wave][quad * 4 + r][16 + col] = f2bf_u(p1);
        }
        #pragma unroll
        for (int ht = 0; ht < 4; ht++) {
            #pragma unroll
            for (int r = 0; r < 4; r++) o[ht][r] *= alpha[r];
        }
        // P back in A layout (wave-private LDS round trip; compiler orders ds ops)
        bf16x8 pf = *(const bf16x8*)&plds[wave][col][quad * 8];
        #pragma unroll
        for (int ht = 0; ht < 4; ht++) {
            bf16x8 vf = *(const bf16x8*)(vb + (size_t)(ht * 16 + col) * T_ + s0 + quad * 8);
            o[ht] = __builtin_amdgcn_mfma_f32_16x16x32_bf16(pf, vf, o[ht], 0, 0, 0);
        }
    }
    #pragma unroll
    for (int r = 0; r < 4; r++) {
        float inv = 1.0f / lr[r];
        int t = t0 + quad * 4 + r;
        #pragma unroll
        for (int ht = 0; ht < 4; ht++) {
            out[((size_t)bi * T_ + t) * 64 + ht * 16 + col] = o[ht][r] * inv;
        }
    }
}

extern "C" void kernel_launch(void* const* d_in, const int* in_sizes, int n_in,
                              void* d_out, int out_size, void* d_ws, size_t ws_size,
                              hipStream_t stream) {
    const float* x  = (const float*)d_in[0];
    const float* Wq = (const float*)d_in[1];
    const float* Wk = (const float*)d_in[2];
    const float* Wv = (const float*)d_in[3];
    float* out = (float*)d_out;

    // workspace layout (bf16 buffers): Wp 384KB | q 2MB | k 2MB | vT 2MB
    unsigned short* Wp  = (unsigned short*)d_ws;
    unsigned short* qws = (unsigned short*)((char*)d_ws + 0x60000);
    unsigned short* kws = (unsigned short*)((char*)d_ws + 0x60000 + 0x200000);
    unsigned short* vws = (unsigned short*)((char*)d_ws + 0x60000 + 0x400000);

    prep_w_kernel<<<(C_ * 192 + 255) / 256, 256, 0, stream>>>(Wq, Wk, Wv, Wp);
    proj_kernel<<<(B_ * T_) / 64, 256, 0, stream>>>(x, Wp, qws, kws, vws);
    attn_kernel<<<(B_ * T_) / 64, 256, 0, stream>>>(qws, kws, vws, out);
}